// Round 1
// baseline (412.435 us; speedup 1.0000x reference)
//
#include <hip/hip_runtime.h>
#include <stdint.h>

#define BB   2
#define SS   2048
#define DD   1024
#define HH   16
#define DKK  64
#define MM   (BB*SS)   // 4096 rows total

typedef __attribute__((ext_vector_type(4))) float f32x4;
typedef __attribute__((ext_vector_type(8))) short s16x8;

#define MFMA_B16(a, b, c) __builtin_amdgcn_mfma_f32_16x16x32_bf16((a), (b), (c), 0, 0, 0)

__device__ __forceinline__ ushort f2bf(float f) {
  uint u = __float_as_uint(f);
  u += 0x7FFFu + ((u >> 16) & 1u);   // round-to-nearest-even
  return (ushort)(u >> 16);
}

// ---------------- fp32 -> bf16 convert (8 elems/thread) ----------------
__global__ void cvt_kernel(const float* __restrict__ src, ushort* __restrict__ dst, int n) {
  int i = (blockIdx.x * 256 + threadIdx.x) * 8;
  if (i >= n) return;
  const float4* s4 = (const float4*)(src + i);
  float4 a = s4[0], b = s4[1];
  union { ushort u[8]; s16x8 v; } r;
  r.u[0] = f2bf(a.x); r.u[1] = f2bf(a.y); r.u[2] = f2bf(a.z); r.u[3] = f2bf(a.w);
  r.u[4] = f2bf(b.x); r.u[5] = f2bf(b.y); r.u[6] = f2bf(b.z); r.u[7] = f2bf(b.w);
  *(s16x8*)(dst + i) = r.v;
}

// ---------------- combine split-K partials + convert ----------------
__global__ void combine_kernel(const float* __restrict__ p0, const float* __restrict__ p1,
                               ushort* __restrict__ dst, int n) {
  int i = (blockIdx.x * 256 + threadIdx.x) * 8;
  if (i >= n) return;
  const float4* a4 = (const float4*)(p0 + i);
  const float4* b4 = (const float4*)(p1 + i);
  float4 a0 = a4[0], a1 = a4[1], b0 = b4[0], b1 = b4[1];
  union { ushort u[8]; s16x8 v; } r;
  r.u[0] = f2bf(a0.x + b0.x); r.u[1] = f2bf(a0.y + b0.y);
  r.u[2] = f2bf(a0.z + b0.z); r.u[3] = f2bf(a0.w + b0.w);
  r.u[4] = f2bf(a1.x + b1.x); r.u[5] = f2bf(a1.y + b1.y);
  r.u[6] = f2bf(a1.z + b1.z); r.u[7] = f2bf(a1.w + b1.w);
  *(s16x8*)(dst + i) = r.v;
}

// ---------------- Y = A @ W^T  (A:[4096,1024] bf16, W:[1024,1024] bf16) ----------------
// mode 0: Q-proj -> [B,H,S,DK] bf16, scaled by 1/8
// mode 1: K-proj -> [B,H,S,DK] bf16
// mode 2: V-proj -> [B,H,DK,S] bf16 (transposed)
// mode 3: O-proj -> [4096,1024] fp32 (d_out)
__global__ __launch_bounds__(256, 2) void proj_gemm(
    const ushort* __restrict__ A, const ushort* __restrict__ W,
    void* __restrict__ outp, int mode)
{
  __shared__ ushort As[128 * 32];
  __shared__ ushort Bs[128 * 32];
  const int tid  = threadIdx.x;
  const int lane = tid & 63, wave = tid >> 6;
  const int q = lane & 15, g = lane >> 4;
  const int wr = wave >> 1, wc = wave & 1;
  const int mblk = blockIdx.x * 128, nblk = blockIdx.y * 128;

  f32x4 acc[4][4];
  {
    f32x4 z = {0.f, 0.f, 0.f, 0.f};
#pragma unroll
    for (int i = 0; i < 4; ++i)
#pragma unroll
      for (int j = 0; j < 4; ++j) acc[i][j] = z;
  }

  const int r0 = tid >> 2;            // staging row
  const int e0 = (tid & 3) * 8;       // staging element offset within row
  for (int k0 = 0; k0 < 1024; k0 += 32) {
#pragma unroll
    for (int it = 0; it < 2; ++it) {
      const int row = r0 + it * 64;
      *(s16x8*)&As[row * 32 + e0] = *(const s16x8*)(A + (size_t)(mblk + row) * 1024 + k0 + e0);
      *(s16x8*)&Bs[row * 32 + e0] = *(const s16x8*)(W + (size_t)(nblk + row) * 1024 + k0 + e0);
    }
    __syncthreads();
    s16x8 af[4], bf[4];
#pragma unroll
    for (int t = 0; t < 4; ++t) {
      af[t] = *(const s16x8*)&As[(wr * 64 + t * 16 + q) * 32 + g * 8];
      bf[t] = *(const s16x8*)&Bs[(wc * 64 + t * 16 + q) * 32 + g * 8];
    }
#pragma unroll
    for (int mt = 0; mt < 4; ++mt)
#pragma unroll
      for (int nt = 0; nt < 4; ++nt)
        acc[mt][nt] = MFMA_B16(af[mt], bf[nt], acc[mt][nt]);
    __syncthreads();
  }

  // epilogue: C layout col = lane&15 (N), row = (lane>>4)*4 + j (M)
  if (mode == 3) {
    float* O = (float*)outp;
#pragma unroll
    for (int mt = 0; mt < 4; ++mt)
#pragma unroll
      for (int nt = 0; nt < 4; ++nt)
#pragma unroll
        for (int j = 0; j < 4; ++j) {
          const int s = mblk + wr * 64 + mt * 16 + g * 4 + j;
          const int o = nblk + wc * 64 + nt * 16 + q;
          O[(size_t)s * DD + o] = acc[mt][nt][j];
        }
  } else if (mode == 2) {
    ushort* Vt = (ushort*)outp;
#pragma unroll
    for (int mt = 0; mt < 4; ++mt)
#pragma unroll
      for (int nt = 0; nt < 4; ++nt) {
        const int s0 = mblk + wr * 64 + mt * 16 + g * 4;
        const int o  = nblk + wc * 64 + nt * 16 + q;
        const int h = o >> 6, dk = o & 63;
        const int b = s0 >> 11, sr = s0 & 2047;
        ushort4 pk;
        pk.x = f2bf(acc[mt][nt][0]); pk.y = f2bf(acc[mt][nt][1]);
        pk.z = f2bf(acc[mt][nt][2]); pk.w = f2bf(acc[mt][nt][3]);
        *(ushort4*)(Vt + ((size_t)((b * 16 + h) * 64 + dk)) * SS + sr) = pk;
      }
  } else {
    const float scale = (mode == 0) ? 0.125f : 1.0f;
    ushort* P = (ushort*)outp;
#pragma unroll
    for (int mt = 0; mt < 4; ++mt)
#pragma unroll
      for (int nt = 0; nt < 4; ++nt)
#pragma unroll
        for (int j = 0; j < 4; ++j) {
          const int s = mblk + wr * 64 + mt * 16 + g * 4 + j;
          const int o = nblk + wc * 64 + nt * 16 + q;
          const int h = o >> 6, dk = o & 63;
          const int b = s >> 11, sr = s & 2047;
          P[((size_t)(b * 16 + h) * SS + sr) * DKK + dk] = f2bf(acc[mt][nt][j] * scale);
        }
  }
}

// ---------------- fused attention with head-axis softmax ----------------
// grid 256: b(2) x qb(64) x sk(2).  block 512 = 8 waves: wh = wave>>1 (head group
// of 4), qi = wave&1 (q-subtile of 16).  Iterates 32 keys/iter over its 1024-key
// chunk.  Scores via swapped MFMA (S^T = K·Q^T) so softmax-over-h is lane-local;
// cross-wave denominator via LDS partial sums; attn re-layout via swizzled LDS.
__global__ __launch_bounds__(512, 2) void attn_kernel(
    const ushort* __restrict__ Qp, const ushort* __restrict__ Kp,
    const ushort* __restrict__ Vt, float* __restrict__ Part)
{
  __shared__ float  psum[4096];      // [qi][ksub][r][g][q][slot4] fp32, 16 KB
  __shared__ ushort attn_sm[16384];  // [wave][i4][q16][k32 swizzled] bf16, 32 KB

  const int tid  = threadIdx.x;
  const int lane = tid & 63;
  const int wave = tid >> 6;
  const int wh = wave >> 1;
  const int qi = wave & 1;
  const int q  = lane & 15;
  const int g  = lane >> 4;
  const int bid = blockIdx.x;
  const int b   = bid >> 7;
  const int qb  = (bid & 127) >> 1;
  const int sk  = bid & 1;
  const int qrow = qb * 32 + qi * 16;
  const int k0   = sk * 1024;

  // hoist Q fragments (B-operand layout: col=lane&15 -> q, inner d contiguous)
  s16x8 qf[4][2];
#pragma unroll
  for (int i = 0; i < 4; ++i) {
    const int h = wh * 4 + i;
    const ushort* Qb = Qp + ((size_t)(b * 16 + h) * SS + qrow + q) * DKK + g * 8;
#pragma unroll
    for (int dh = 0; dh < 2; ++dh) qf[i][dh] = *(const s16x8*)(Qb + dh * 32);
  }

  f32x4 acc[4][4];
  {
    f32x4 z = {0.f, 0.f, 0.f, 0.f};
#pragma unroll
    for (int i = 0; i < 4; ++i)
#pragma unroll
      for (int n = 0; n < 4; ++n) acc[i][n] = z;
  }

  ushort* aw = attn_sm + wave * 2048;
  const int swz = (q & 3) << 4;

  for (int kt = 0; kt < 32; ++kt) {
    const int krow = k0 + kt * 32;
    float e[4][2][4];
    float ps0[4] = {0.f, 0.f, 0.f, 0.f};
    float ps1[4] = {0.f, 0.f, 0.f, 0.f};
#pragma unroll
    for (int i = 0; i < 4; ++i) {
      const int h = wh * 4 + i;
      const ushort* Kb = Kp + ((size_t)(b * 16 + h) * SS + krow + q) * DKK + g * 8;
      f32x4 c0 = {0.f, 0.f, 0.f, 0.f}, c1 = {0.f, 0.f, 0.f, 0.f};
      c0 = MFMA_B16(*(const s16x8*)(Kb), qf[i][0], c0);
      c0 = MFMA_B16(*(const s16x8*)(Kb + 32), qf[i][1], c0);
      c1 = MFMA_B16(*(const s16x8*)(Kb + 16 * DKK), qf[i][0], c1);
      c1 = MFMA_B16(*(const s16x8*)(Kb + 16 * DKK + 32), qf[i][1], c1);
#pragma unroll
      for (int r = 0; r < 4; ++r) {
        e[i][0][r] = __expf(c0[r]); ps0[r] += e[i][0][r];
        e[i][1][r] = __expf(c1[r]); ps1[r] += e[i][1][r];
      }
    }
    // write per-wave partial denominators (slot = wh^g keeps banks 2-way)
    const int slot = wh ^ g;
#pragma unroll
    for (int r = 0; r < 4; ++r) {
      psum[((((qi * 2 + 0) * 4 + r) * 4 + g) * 16 + q) * 4 + slot] = ps0[r];
      psum[((((qi * 2 + 1) * 4 + r) * 4 + g) * 16 + q) * 4 + slot] = ps1[r];
    }
    __syncthreads();
    float rinv[2][4];
#pragma unroll
    for (int ks = 0; ks < 2; ++ks)
#pragma unroll
      for (int r = 0; r < 4; ++r) {
        f32x4 t = *(const f32x4*)&psum[((((qi * 2 + ks) * 4 + r) * 4 + g) * 16 + q) * 4];
        rinv[ks][r] = 1.0f / (t[0] + t[1] + t[2] + t[3]);
      }
    // normalized attn -> LDS (bf16), XOR-swizzled within the 64B q-row
#pragma unroll
    for (int i = 0; i < 4; ++i) {
      const int rowoff = (i * 16 + q) * 64;
#pragma unroll
      for (int ks = 0; ks < 2; ++ks) {
        uint2 pp;
        pp.x = (uint)f2bf(e[i][ks][0] * rinv[ks][0]) | ((uint)f2bf(e[i][ks][1] * rinv[ks][1]) << 16);
        pp.y = (uint)f2bf(e[i][ks][2] * rinv[ks][2]) | ((uint)f2bf(e[i][ks][3] * rinv[ks][3]) << 16);
        *(uint2*)((char*)aw + rowoff + ((ks * 32 + g * 8) ^ swz)) = pp;
      }
    }
    __syncthreads();
    // PV: A = attn (row=q, 8 consecutive k per lane), B = V^T rows from Vt
#pragma unroll
    for (int i = 0; i < 4; ++i) {
      const int h = wh * 4 + i;
      s16x8 pa = *(const s16x8*)((char*)aw + (i * 16 + q) * 64 + ((g * 16) ^ swz));
      const ushort* Vb = Vt + ((size_t)(b * 16 + h) * DKK + q) * SS + krow + g * 8;
#pragma unroll
      for (int n = 0; n < 4; ++n)
        acc[i][n] = MFMA_B16(pa, *(const s16x8*)(Vb + n * 16 * SS), acc[i][n]);
    }
    __syncthreads();
  }

  // epilogue: partial ctx, fp32, layout [sk][4096][1024]
  float* P = Part + (size_t)sk * MM * DD + ((size_t)(b * SS) + qrow) * DD;
#pragma unroll
  for (int i = 0; i < 4; ++i) {
    const int colbase = (wh * 4 + i) * 64;
#pragma unroll
    for (int n = 0; n < 4; ++n)
#pragma unroll
      for (int j = 0; j < 4; ++j)
        P[(size_t)(g * 4 + j) * DD + colbase + n * 16 + q] = acc[i][n][j];
  }
}

extern "C" void kernel_launch(void* const* d_in, const int* in_sizes, int n_in,
                              void* d_out, int out_size, void* d_ws, size_t ws_size,
                              hipStream_t stream) {
  const float* Query = (const float*)d_in[0];
  const float* Key   = (const float*)d_in[1];
  const float* Value = (const float*)d_in[2];
  const float* Wq    = (const float*)d_in[3];
  const float* Wk    = (const float*)d_in[4];
  const float* Wv    = (const float*)d_in[5];
  const float* Wo    = (const float*)d_in[6];

  size_t off = 0;
  char* ws = (char*)d_ws;
  auto alloc = [&](size_t bytes) -> void* {
    void* p = ws + off;
    off += (bytes + 255) & ~(size_t)255;
    return p;
  };
  const size_t nX = (size_t)MM * DD;   // 4194304
  const size_t nW = (size_t)DD * DD;   // 1048576
  ushort* Xq  = (ushort*)alloc(nX * 2);
  ushort* Xk  = (ushort*)alloc(nX * 2);
  ushort* Xv  = (ushort*)alloc(nX * 2);
  ushort* Wqb = (ushort*)alloc(nW * 2);
  ushort* Wkb = (ushort*)alloc(nW * 2);
  ushort* Wvb = (ushort*)alloc(nW * 2);
  ushort* Wob = (ushort*)alloc(nW * 2);
  ushort* Qp  = (ushort*)alloc(nX * 2);
  ushort* Kp  = (ushort*)alloc(nX * 2);
  ushort* Vtb = (ushort*)alloc(nX * 2);
  float*  Part = (float*)alloc(2 * nX * 4);
  ushort* Ctx = (ushort*)alloc(nX * 2);

  cvt_kernel<<<(int)(nX / 2048), 256, 0, stream>>>(Query, Xq, (int)nX);
  cvt_kernel<<<(int)(nX / 2048), 256, 0, stream>>>(Key,   Xk, (int)nX);
  cvt_kernel<<<(int)(nX / 2048), 256, 0, stream>>>(Value, Xv, (int)nX);
  cvt_kernel<<<(int)(nW / 2048), 256, 0, stream>>>(Wq, Wqb, (int)nW);
  cvt_kernel<<<(int)(nW / 2048), 256, 0, stream>>>(Wk, Wkb, (int)nW);
  cvt_kernel<<<(int)(nW / 2048), 256, 0, stream>>>(Wv, Wvb, (int)nW);
  cvt_kernel<<<(int)(nW / 2048), 256, 0, stream>>>(Wo, Wob, (int)nW);

  dim3 pg(32, 8), pb(256);
  proj_gemm<<<pg, pb, 0, stream>>>(Xq, Wqb, Qp, 0);
  proj_gemm<<<pg, pb, 0, stream>>>(Xk, Wkb, Kp, 1);
  proj_gemm<<<pg, pb, 0, stream>>>(Xv, Wvb, Vtb, 2);

  attn_kernel<<<256, 512, 0, stream>>>(Qp, Kp, Vtb, Part);

  combine_kernel<<<(int)(nX / 2048), 256, 0, stream>>>(Part, Part + nX, Ctx, (int)nX);

  proj_gemm<<<pg, pb, 0, stream>>>(Ctx, Wob, d_out, 3);
}